// Round 1
// baseline (13174.297 us; speedup 1.0000x reference)
//
#include <hip/hip_runtime.h>
#include <math.h>

#define LDIM 384
#define NPIX (LDIM*LDIM)
#define HID 64
#define NBINS 63

__device__ __forceinline__ float eluf(float x){ return x > 0.f ? x : expm1f(x); }
__device__ __forceinline__ float sigf(float x){ return 1.f/(1.f+expf(-x)); }

// ---------------- input 1x1 conv: NHWC(41) -> NCHW(64) ----------------
__global__ __launch_bounds__(256) void in_proj_kernel(
    const float* __restrict__ feat, const float* __restrict__ w,
    const float* __restrict__ b, float* __restrict__ out){
  int pix = blockIdx.x*256 + threadIdx.x;
  float f[41];
  const float* fp = feat + (size_t)pix*41;
  #pragma unroll
  for(int k=0;k<41;k++) f[k] = fp[k];
  for(int c=0;c<64;c++){
    const float* wr = w + c*41;
    float acc = b[c];
    #pragma unroll
    for(int k=0;k<41;k++) acc += f[k]*wr[k];
    out[c*NPIX + pix] = acc;
  }
}

// ---------------- generic 3x3 dilated conv, NCHW, 4 oc / block ----------------
// act: 0 = none, 1 = relu
__global__ __launch_bounds__(256) void conv3x3_kernel(
    const float* __restrict__ in, const float* __restrict__ w,
    const float* __restrict__ bias, float* __restrict__ out,
    int IC, int OC, int dil, int act){
  extern __shared__ float s_in[];
  const int tx = threadIdx.x & 15, ty = threadIdx.x >> 4;
  const int ox = blockIdx.x*16 + tx, oy = blockIdx.y*16 + ty;
  const int oc0 = blockIdx.z*4;
  const int tsz = 16 + 2*dil;
  int ocl[4];
  #pragma unroll
  for(int m=0;m<4;m++){ int o = oc0+m; ocl[m] = (o < OC) ? o : (OC-1); }
  float acc[4] = {0.f,0.f,0.f,0.f};
  for(int ic=0; ic<IC; ic++){
    const float* inp = in + (size_t)ic*NPIX;
    for(int ly=ty; ly<tsz; ly+=16){
      int gy = blockIdx.y*16 + ly - dil;
      for(int lx=tx; lx<tsz; lx+=16){
        int gx = blockIdx.x*16 + lx - dil;
        float v = 0.f;
        if((unsigned)gy < LDIM && (unsigned)gx < LDIM) v = inp[gy*LDIM + gx];
        s_in[ly*tsz + lx] = v;
      }
    }
    __syncthreads();
    float iv[9];
    #pragma unroll
    for(int ky=0;ky<3;ky++)
      #pragma unroll
      for(int kx=0;kx<3;kx++)
        iv[ky*3+kx] = s_in[(ty + dil*ky)*tsz + tx + dil*kx];
    #pragma unroll
    for(int m=0;m<4;m++){
      const float* wp = w + ((size_t)ocl[m]*IC + ic)*9;
      float a = acc[m];
      #pragma unroll
      for(int k=0;k<9;k++) a += iv[k]*wp[k];
      acc[m] = a;
    }
    __syncthreads();
  }
  int o = oy*LDIM + ox;
  #pragma unroll
  for(int m=0;m<4;m++){
    if(oc0+m < OC){
      float r = acc[m] + bias[ocl[m]];
      if(act==1) r = fmaxf(r, 0.f);
      out[(size_t)(oc0+m)*NPIX + o] = r;
    }
  }
}

// ---------------- per-channel instance-norm stats ----------------
__global__ __launch_bounds__(256) void stats_kernel(
    const float* __restrict__ x, float* __restrict__ stats){
  int c = blockIdx.x;
  const float* p = x + (size_t)c*NPIX;
  float s=0.f, sq=0.f;
  for(int i=threadIdx.x; i<NPIX; i+=256){ float v = p[i]; s += v; sq += v*v; }
  __shared__ float ss[256], sqq[256];
  ss[threadIdx.x]=s; sqq[threadIdx.x]=sq;
  __syncthreads();
  for(int st=128; st>0; st>>=1){
    if(threadIdx.x<st){ ss[threadIdx.x]+=ss[threadIdx.x+st]; sqq[threadIdx.x]+=sqq[threadIdx.x+st]; }
    __syncthreads();
  }
  if(threadIdx.x==0){
    float mu = ss[0]*(1.0f/NPIX);
    float var = sqq[0]*(1.0f/NPIX) - mu*mu;
    stats[2*c]   = mu;
    stats[2*c+1] = rsqrtf(var + 1e-5f);
  }
}

__global__ __launch_bounds__(256) void norm_elu_kernel(
    float* __restrict__ x, const float* __restrict__ stats){
  int c = blockIdx.y;
  int i = blockIdx.x*256 + threadIdx.x;
  float mu = stats[2*c], rs = stats[2*c+1];
  size_t idx = (size_t)c*NPIX + i;
  x[idx] = eluf((x[idx]-mu)*rs);
}

__global__ __launch_bounds__(256) void norm_res_elu_kernel(
    const float* __restrict__ t, float* __restrict__ x, const float* __restrict__ stats){
  int c = blockIdx.y;
  int i = blockIdx.x*256 + threadIdx.x;
  float mu = stats[2*c], rs = stats[2*c+1];
  size_t idx = (size_t)c*NPIX + i;
  x[idx] = eluf((t[idx]-mu)*rs + x[idx]);
}

// ---------------- attention: scalar gate g ----------------
__global__ __launch_bounds__(256) void g_kernel(
    const float* __restrict__ td, const float* __restrict__ tq,
    const float* __restrict__ w1, const float* __restrict__ b1,
    const float* __restrict__ w2, const float* __restrict__ b2,
    float* __restrict__ gout){
  __shared__ float red[256];
  float cnt=0.f;
  for(int i=threadIdx.x;i<NPIX;i+=256) cnt += (td[i]>0.f)?1.f:0.f;
  red[threadIdx.x]=cnt; __syncthreads();
  for(int st=128;st>0;st>>=1){ if(threadIdx.x<st) red[threadIdx.x]+=red[threadIdx.x+st]; __syncthreads(); }
  if(threadIdx.x==0){
    float f0 = red[0]*(1.0f/NPIX);
    float f1 = tq[0];
    float f2 = (float)LDIM/512.0f;
    float z = b2[0];
    for(int j=0;j<16;j++){
      float h = f0*w1[j] + f1*w1[16+j] + f2*w1[32+j] + b1[j];
      h = h>0.f?h:0.f;
      z += h*w2[j];
    }
    gout[0] = sigf(z);
  }
}

// q[pix][n] = sum_c x[c][pix] * wq[c][n]
__global__ __launch_bounds__(256) void q_proj_kernel(
    const float* __restrict__ x, const float* __restrict__ wq, float* __restrict__ q){
  __shared__ float xs[64][64];
  __shared__ float wsh[2048];
  int pb = blockIdx.x*64;
  for(int idx=threadIdx.x; idx<4096; idx+=256){
    int c = idx>>6, p = idx&63;
    xs[c][p] = x[(size_t)c*NPIX + pb + p];
  }
  for(int idx=threadIdx.x; idx<2048; idx+=256) wsh[idx]=wq[idx];
  __syncthreads();
  #pragma unroll
  for(int k=0;k<8;k++){
    int idx = threadIdx.x + k*256;
    int p = idx>>5, n = idx&31;
    float acc=0.f;
    #pragma unroll
    for(int c=0;c<64;c++) acc += xs[c][p]*wsh[c*32+n];
    q[(size_t)(pb+p)*32 + n] = acc;
  }
}

// left/vleft[i][a][n] = sum_c x[c][i][12a] * w[c][n]
__global__ __launch_bounds__(256) void proj_left_kernel(
    const float* __restrict__ x, const float* __restrict__ wl, const float* __restrict__ wvl,
    float* __restrict__ left, float* __restrict__ vleft){
  int i = blockIdx.x;
  __shared__ float xa[64][33];
  __shared__ float w1s[2048], w2s[2048];
  for(int idx=threadIdx.x; idx<2048; idx+=256){
    int c=idx>>5, a=idx&31;
    xa[c][a] = x[(size_t)c*NPIX + i*LDIM + 12*a];
    w1s[idx] = wl[idx];
    w2s[idx] = wvl[idx];
  }
  __syncthreads();
  #pragma unroll
  for(int k=0;k<4;k++){
    int idx = threadIdx.x + k*256;
    int a = idx>>5, n = idx&31;
    float a1=0.f,a2=0.f;
    #pragma unroll
    for(int c=0;c<64;c++){ float v=xa[c][a]; a1 += v*w1s[c*32+n]; a2 += v*w2s[c*32+n]; }
    left [(size_t)(i*32+a)*32+n] = a1;
    vleft[(size_t)(i*32+a)*32+n] = a2;
  }
}

// right/vright stored [j][a][n] = sum_c x[c][12a][j] * w[c][n]
__global__ __launch_bounds__(256) void proj_right_kernel(
    const float* __restrict__ x, const float* __restrict__ wr, const float* __restrict__ wvr,
    float* __restrict__ right, float* __restrict__ vright){
  int a = blockIdx.x;
  int row = 12*a;
  __shared__ float xr[64][33];
  __shared__ float w1s[2048], w2s[2048];
  for(int idx=threadIdx.x; idx<2048; idx+=256){ w1s[idx]=wr[idx]; w2s[idx]=wvr[idx]; }
  for(int j0=0;j0<LDIM;j0+=32){
    __syncthreads();
    for(int idx=threadIdx.x; idx<2048; idx+=256){
      int c=idx>>5, jl=idx&31;
      xr[c][jl] = x[(size_t)c*NPIX + row*LDIM + j0+jl];
    }
    __syncthreads();
    #pragma unroll
    for(int k=0;k<4;k++){
      int idx=threadIdx.x + k*256;
      int jl=idx>>5, n=idx&31;
      float a1=0.f,a2=0.f;
      #pragma unroll
      for(int c=0;c<64;c++){ float v=xr[c][jl]; a1+=v*w1s[c*32+n]; a2+=v*w2s[c*32+n]; }
      right [(size_t)((j0+jl)*32 + a)*32 + n] = a1;
      vright[(size_t)((j0+jl)*32 + a)*32 + n] = a2;
    }
  }
}

// scores + bias + softmax -> attn[pix][a]
__global__ __launch_bounds__(128) void scores_kernel(
    const float* __restrict__ q, const float* __restrict__ left,
    const float* __restrict__ right, const float* __restrict__ td,
    const float* __restrict__ gp, float* __restrict__ attn){
  int i = blockIdx.y;
  int j = blockIdx.x*128 + threadIdx.x;
  __shared__ float lf[1024];
  __shared__ float tl[32];
  for(int idx=threadIdx.x; idx<1024; idx+=128) lf[idx] = left[(size_t)i*1024 + idx];
  if(threadIdx.x<32) tl[threadIdx.x] = td[i*LDIM + 12*threadIdx.x];
  __syncthreads();
  float g = gp[0];
  float qv[32];
  const float* qp = q + (size_t)(i*LDIM+j)*32;
  #pragma unroll
  for(int n=0;n<32;n++) qv[n]=qp[n];
  float tdij = td[i*LDIM+j];
  float s[32];
  const float* rp = right + (size_t)j*1024;
  float m = -1e30f;
  #pragma unroll
  for(int a=0;a<32;a++){
    float acc=0.f;
    #pragma unroll
    for(int n=0;n<32;n++) acc += qv[n]*lf[a*32+n];
    #pragma unroll
    for(int n=0;n<32;n++) acc += qv[n]*rp[a*32+n];
    acc *= 0.17677669529663687f; // 1/sqrt(32)
    float tr = td[(12*a)*LDIM + j];
    float bias = -fabsf(tl[a] + tr - tdij) * (1.0f/12.0f);
    acc += g*bias;
    s[a]=acc;
    m = fmaxf(m, acc);
  }
  float sum=0.f;
  #pragma unroll
  for(int a=0;a<32;a++){ s[a]=expf(s[a]-m); sum+=s[a]; }
  float inv = 1.f/sum;
  float* op = attn + (size_t)(i*LDIM+j)*32;
  #pragma unroll
  for(int a=0;a<32;a++) op[a] = s[a]*inv;
}

// upd[pix][n] = sum_a attn[pix][a]*(vleft[i][a][n]) + sum_a attn[pix][a]*vright[j][a][n]
__global__ __launch_bounds__(256) void update_kernel(
    const float* __restrict__ attn, const float* __restrict__ vleft,
    const float* __restrict__ vright, float* __restrict__ upd){
  int i = blockIdx.y;
  int j0 = blockIdx.x*8;
  int p = threadIdx.x>>5, n = threadIdx.x&31;
  __shared__ float at[8][32];
  __shared__ float vl[1024];
  at[p][n] = attn[(size_t)(i*LDIM + j0+p)*32 + n];
  for(int idx=threadIdx.x; idx<1024; idx+=256) vl[idx]=vleft[(size_t)i*1024+idx];
  __syncthreads();
  const float* vr = vright + (size_t)(j0+p)*1024;
  float acc=0.f;
  #pragma unroll
  for(int a=0;a<32;a++){
    float w = at[p][a];
    acc += w*vl[a*32+n];
    acc += w*vr[a*32+n];
  }
  upd[(size_t)(i*LDIM + j0+p)*32 + n] = acc;
}

// x[c][pix] += sigmoid(x·wg + bg) * (upd·wo)
__global__ __launch_bounds__(256) void gate_out_kernel(
    float* __restrict__ x, const float* __restrict__ upd,
    const float* __restrict__ wg, const float* __restrict__ bg,
    const float* __restrict__ wo){
  __shared__ float wgs[4096];
  __shared__ float wos[2048];
  __shared__ float xs[64][17];
  __shared__ float us[32][17];
  int pb = blockIdx.x*16;
  for(int idx=threadIdx.x; idx<4096; idx+=256) wgs[idx]=wg[idx];
  for(int idx=threadIdx.x; idx<2048; idx+=256) wos[idx]=wo[idx];
  for(int idx=threadIdx.x; idx<1024; idx+=256){
    int c=idx>>4, p=idx&15;
    xs[c][p] = x[(size_t)c*NPIX + pb + p];
  }
  for(int idx=threadIdx.x; idx<512; idx+=256){
    int n=idx>>4, p=idx&15;
    us[n][p] = upd[(size_t)(pb+p)*32 + n];
  }
  __syncthreads();
  #pragma unroll
  for(int k=0;k<4;k++){
    int item = threadIdx.x + k*256;
    int p = item&15, c = item>>4;
    float gacc = bg[c];
    #pragma unroll
    for(int cc=0;cc<64;cc++) gacc += xs[cc][p]*wgs[cc*64+c];
    float uacc=0.f;
    #pragma unroll
    for(int n=0;n<32;n++) uacc += us[n][p]*wos[n*64+c];
    x[(size_t)c*NPIX + pb + p] = xs[c][p] + sigf(gacc)*uacc;
  }
}

// symmetrize logits; write NCHW sym buffer + transposed fp32 output
__global__ __launch_bounds__(256) void sym_kernel(
    const float* __restrict__ lg, float* __restrict__ symb, float* __restrict__ dout){
  int o = blockIdx.y;
  int idx = blockIdx.x*256 + threadIdx.x;
  int i = idx / LDIM, j = idx - i*LDIM;
  float v = 0.5f*(lg[(size_t)o*NPIX + i*LDIM + j] + lg[(size_t)o*NPIX + j*LDIM + i]);
  symb[(size_t)o*NPIX + idx] = v;
  dout[(size_t)idx*NBINS + o] = v;
}

// final 1x1 conv 32->1 + sigmoid
__global__ __launch_bounds__(256) void conf_kernel(
    const float* __restrict__ c2, const float* __restrict__ w,
    const float* __restrict__ b, float* __restrict__ out){
  int pix = blockIdx.x*256 + threadIdx.x;
  float acc = b[0];
  #pragma unroll
  for(int c=0;c<32;c++) acc += c2[(size_t)c*NPIX+pix]*w[c];
  out[pix] = sigf(acc);
}

extern "C" void kernel_launch(void* const* d_in, const int* in_sizes, int n_in,
                              void* d_out, int out_size, void* d_ws, size_t ws_size,
                              hipStream_t stream){
  const float* feat = (const float*)d_in[0];
  const float* td   = (const float*)d_in[1];
  const float* tq   = (const float*)d_in[2];
  const float* in_w = (const float*)d_in[3];
  const float* in_b = (const float*)d_in[4];
  const float* c1w  = (const float*)d_in[5];
  const float* c1b  = (const float*)d_in[6];
  const float* c2w  = (const float*)d_in[7];
  const float* c2b  = (const float*)d_in[8];
  const float* wq   = (const float*)d_in[9];
  const float* wl   = (const float*)d_in[10];
  const float* wr   = (const float*)d_in[11];
  const float* wvl  = (const float*)d_in[12];
  const float* wvr  = (const float*)d_in[13];
  const float* wo   = (const float*)d_in[14];
  const float* wg   = (const float*)d_in[15];
  const float* bg   = (const float*)d_in[16];
  const float* tgw1 = (const float*)d_in[17];
  const float* tgb1 = (const float*)d_in[18];
  const float* tgw2 = (const float*)d_in[19];
  const float* tgb2 = (const float*)d_in[20];
  const float* dw   = (const float*)d_in[21];
  const float* db   = (const float*)d_in[22];
  const float* cf1w = (const float*)d_in[23];
  const float* cf1b = (const float*)d_in[24];
  const float* cf2w = (const float*)d_in[25];
  const float* cf2b = (const float*)d_in[26];
  const float* cf3w = (const float*)d_in[27];
  const float* cf3b = (const float*)d_in[28];

  float* ws = (float*)d_ws;
  const size_t BUF = (size_t)64*NPIX; // 9437184
  float* X   = ws;
  float* T1  = ws + BUF;
  float* T2  = ws + 2*BUF;
  float* STATS = ws + 3*BUF;   // 128 floats
  float* G     = STATS + 128;  // 1 float
  // attention temporaries live inside T1/T2 (both free during attention)
  float* Q      = T1;                    // 32*NPIX
  float* LEFTB  = T1 + (size_t)32*NPIX;  // 384*32*32
  float* RIGHTB = LEFTB + 393216;
  float* VLEFT  = RIGHTB + 393216;
  float* VRIGHT = VLEFT + 393216;
  float* ATTN   = T2;                    // 32*NPIX
  float* UPD    = T1;                    // reuse Q region after scores

  in_proj_kernel<<<576, 256, 0, stream>>>(feat, in_w, in_b, X);

  const int dils[6] = {1,2,4,8,16,1};
  for(int i=0;i<6;i++){
    int d = dils[i];
    size_t sm1 = (size_t)(16+2*d)*(16+2*d)*sizeof(float);
    conv3x3_kernel<<<dim3(24,24,16), 256, sm1, stream>>>(X, c1w + (size_t)i*36864, c1b + i*64, T1, 64, 64, d, 0);
    stats_kernel<<<64, 256, 0, stream>>>(T1, STATS);
    norm_elu_kernel<<<dim3(576,64), 256, 0, stream>>>(T1, STATS);
    conv3x3_kernel<<<dim3(24,24,16), 256, 18*18*4, stream>>>(T1, c2w + (size_t)i*36864, c2b + i*64, T2, 64, 64, 1, 0);
    stats_kernel<<<64, 256, 0, stream>>>(T2, STATS);
    norm_res_elu_kernel<<<dim3(576,64), 256, 0, stream>>>(T2, X, STATS);
    if(i%2==1){
      g_kernel<<<1,256,0,stream>>>(td, tq, tgw1, tgb1, tgw2, tgb2, G);
      q_proj_kernel<<<2304,256,0,stream>>>(X, wq, Q);
      proj_left_kernel<<<384,256,0,stream>>>(X, wl, wvl, LEFTB, VLEFT);
      proj_right_kernel<<<32,256,0,stream>>>(X, wr, wvr, RIGHTB, VRIGHT);
      scores_kernel<<<dim3(3,384),128,0,stream>>>(Q, LEFTB, RIGHTB, td, G, ATTN);
      update_kernel<<<dim3(48,384),256,0,stream>>>(ATTN, VLEFT, VRIGHT, UPD);
      gate_out_kernel<<<9216,256,0,stream>>>(X, UPD, wg, bg, wo);
    }
  }

  // distance head
  conv3x3_kernel<<<dim3(24,24,16), 256, 18*18*4, stream>>>(X, dw, db, T1, 64, 63, 1, 0);
  sym_kernel<<<dim3(576,63),256,0,stream>>>(T1, T2, (float*)d_out);
  // confidence head
  conv3x3_kernel<<<dim3(24,24,8), 256, 18*18*4, stream>>>(T2, cf1w, cf1b, X, 63, 32, 1, 1);
  conv3x3_kernel<<<dim3(24,24,8), 256, 18*18*4, stream>>>(X, cf2w, cf2b, T1, 32, 32, 1, 1);
  conf_kernel<<<576,256,0,stream>>>(T1, cf3w, cf3b, (float*)d_out + (size_t)NPIX*NBINS);
}

// Round 3
// 2558.194 us; speedup vs baseline: 5.1498x; 5.1498x over previous
//
#include <hip/hip_runtime.h>
#include <math.h>

#define LDIM 384
#define NPIX (LDIM*LDIM)
#define NBINS 63

typedef __attribute__((ext_vector_type(8))) __bf16 bf16x8;
typedef __attribute__((ext_vector_type(4))) float floatx4;

__device__ __forceinline__ float eluf(float x){ return x > 0.f ? x : expm1f(x); }
__device__ __forceinline__ float sigf(float x){ return 1.f/(1.f+expf(-x)); }

// Prepped weight fragment layout (bf16): [tap(9)][kc(ICP/32)][nt(NT)][lane(64)][j(8)]
//   value = W[oc = nt*16 + (lane&15)][ic = kc*32 + (lane>>4)*8 + j][ky][kx]
// WF arena offsets (bf16 units):
//   main slot s (0..11): s=2i -> conv1[i], s=2i+1 -> conv2[i], at s*36864
//   dist: 12*36864 = 442368 ; cf1: 479232 ; cf2: 497664 ; total 506880
__global__ __launch_bounds__(256) void prep_kernel(
    const float* __restrict__ c1w, const float* __restrict__ c2w,
    const float* __restrict__ dw, const float* __restrict__ cf1w,
    const float* __restrict__ cf2w, __bf16* __restrict__ Wf){
  int idx = blockIdx.x*256 + threadIdx.x;
  if (idx >= 506880) return;
  const float* src; int ICreal, OCreal, ICP, NT, rel;
  if (idx < 442368){
    int layer = idx / 36864; rel = idx - layer*36864;   // layer in [0,12)
    int i = layer >> 1;                                  // conv block [0,6)
    src = (layer & 1) ? (c2w + (size_t)i*36864) : (c1w + (size_t)i*36864);
    ICreal=64; OCreal=64; ICP=64; NT=4;
  } else if (idx < 479232){
    rel = idx - 442368; src = dw;   ICreal=64; OCreal=63; ICP=64; NT=4;
  } else if (idx < 497664){
    rel = idx - 479232; src = cf1w; ICreal=63; OCreal=32; ICP=64; NT=2;
  } else {
    rel = idx - 497664; src = cf2w; ICreal=32; OCreal=32; ICP=32; NT=2;
  }
  int j = rel & 7, lane = (rel>>3) & 63;
  int r2 = rel >> 9;
  int nt = r2 % NT; int r3 = r2 / NT;
  int KC = ICP/32;
  int kc = r3 % KC; int tap = r3 / KC;
  int k = kc*32 + (lane>>4)*8 + j;
  int n = nt*16 + (lane&15);
  float v = 0.f;
  if (k < ICreal && n < OCreal) v = src[((size_t)n*ICreal + k)*9 + tap];
  Wf[idx] = (__bf16)v;
}

// ---------- MFMA implicit-GEMM 3x3 dilated conv, NHWC fp32 in/out ----------
// Block: 128-px row strip x NT*16 oc. 4 waves x (32px, MT=2 x NT 16x16 tiles).
// A (activations) split hi/lo bf16, staged one input row at a time in LDS.
// B (weights) read directly from prepped global layout (L1/L2-resident).
template<int ICP, int NT>
__global__ __launch_bounds__(256) void mfma_conv(
    const float* __restrict__ X, const __bf16* __restrict__ Wf,
    const float* __restrict__ bias, int OC_real,
    float* __restrict__ out, int d, int relu){
  constexpr int KC = ICP/32;
  constexpr int AP = ICP + 8;            // LDS pitch (bf16) -> conflict-free b128
  constexpr int OCS = NT*16;
  const int t = threadIdx.x;
  const int wave = t>>6, lane = t&63;
  const int q = lane>>4, col16 = lane&15;
  const int y = blockIdx.y;
  const int x0 = blockIdx.x*128;
  const int SW = 128 + 2*d;
  extern __shared__ __align__(16) char smem_raw[];
  __bf16* Ahi = (__bf16*)smem_raw;                 // SW*AP
  __bf16* Alo = Ahi + (size_t)SW*AP;

  floatx4 acc[2][NT];
  #pragma unroll
  for (int a=0;a<2;a++)
    #pragma unroll
    for (int b=0;b<NT;b++){ floatx4 z = {0.f,0.f,0.f,0.f}; acc[a][b]=z; }

  constexpr int CV = ICP/4;              // threads covering one pixel (float4 each)
  const int cbase = (t & (CV-1))*4;
  const int p0 = t / CV;
  constexpr int PSTEP = 256 / CV;

  for (int ky=0; ky<3; ky++){
    int yr = y + (ky-1)*d;
    bool vrow = (yr >= 0) && (yr < LDIM);
    __syncthreads();
    for (int cl = p0; cl < SW; cl += PSTEP){
      int gx = x0 - d + cl;
      floatx4 v = {0.f,0.f,0.f,0.f};
      if (vrow && gx >= 0 && gx < LDIM)
        v = *(const floatx4*)(X + ((size_t)yr*LDIM + gx)*ICP + cbase);
      __bf16 h0=(__bf16)v[0], h1=(__bf16)v[1], h2=(__bf16)v[2], h3=(__bf16)v[3];
      __bf16 l0=(__bf16)(v[0]-(float)h0), l1=(__bf16)(v[1]-(float)h1);
      __bf16 l2=(__bf16)(v[2]-(float)h2), l3=(__bf16)(v[3]-(float)h3);
      __bf16* ph = Ahi + (size_t)cl*AP + cbase;
      __bf16* pl = Alo + (size_t)cl*AP + cbase;
      ph[0]=h0; ph[1]=h1; ph[2]=h2; ph[3]=h3;
      pl[0]=l0; pl[1]=l1; pl[2]=l2; pl[3]=l3;
    }
    __syncthreads();
    #pragma unroll
    for (int kx=0; kx<3; kx++){
      const __bf16* wtap = Wf + (size_t)(ky*3+kx)*KC*NT*512;
      #pragma unroll
      for (int kc=0; kc<KC; kc++){
        int icoff = kc*32 + q*8;
        bf16x8 ah[2], al[2];
        #pragma unroll
        for (int mt=0; mt<2; mt++){
          int cl = wave*32 + mt*16 + col16 + kx*d;
          ah[mt] = *(const bf16x8*)(Ahi + (size_t)cl*AP + icoff);
          al[mt] = *(const bf16x8*)(Alo + (size_t)cl*AP + icoff);
        }
        const __bf16* wkc = wtap + (size_t)kc*NT*512 + lane*8;
        #pragma unroll
        for (int nt=0; nt<NT; nt++){
          bf16x8 bfrag = *(const bf16x8*)(wkc + (size_t)nt*512);
          acc[0][nt] = __builtin_amdgcn_mfma_f32_16x16x32_bf16(ah[0], bfrag, acc[0][nt], 0,0,0);
          acc[1][nt] = __builtin_amdgcn_mfma_f32_16x16x32_bf16(ah[1], bfrag, acc[1][nt], 0,0,0);
          acc[0][nt] = __builtin_amdgcn_mfma_f32_16x16x32_bf16(al[0], bfrag, acc[0][nt], 0,0,0);
          acc[1][nt] = __builtin_amdgcn_mfma_f32_16x16x32_bf16(al[1], bfrag, acc[1][nt], 0,0,0);
        }
      }
    }
  }
  // epilogue: C/D layout col=lane&15 -> oc, row=(lane>>4)*4+reg -> px
  #pragma unroll
  for (int mt=0; mt<2; mt++){
    int pxb = x0 + wave*32 + mt*16 + q*4;
    #pragma unroll
    for (int nt=0; nt<NT; nt++){
      int oc = nt*16 + col16;
      float bv = (oc < OC_real) ? bias[oc] : 0.f;
      #pragma unroll
      for (int r=0; r<4; r++){
        float vv = acc[mt][nt][r] + bv;
        if (relu) vv = fmaxf(vv, 0.f);
        out[((size_t)y*LDIM + pxb + r)*OCS + oc] = vv;
      }
    }
  }
}

// ---------------- input 1x1 conv: NHWC(41) -> NHWC(64) ----------------
__global__ __launch_bounds__(256) void in_proj_kernel(
    const float* __restrict__ feat, const float* __restrict__ w,
    const float* __restrict__ b, float* __restrict__ out){
  __shared__ float sf[16][41];
  __shared__ float sw[64*41];
  int t = threadIdx.x;
  size_t p0 = (size_t)blockIdx.x*16;
  for (int idx=t; idx<2624; idx+=256) sw[idx] = w[idx];
  for (int idx=t; idx<16*41; idx+=256){
    int p = idx/41, k2 = idx - p*41;
    sf[p][k2] = feat[(p0+p)*41 + k2];
  }
  __syncthreads();
  #pragma unroll
  for (int k=0;k<4;k++){
    int item = t + k*256;
    int c = item&63, p = item>>6;
    float acc = b[c];
    #pragma unroll
    for (int kk=0;kk<41;kk++) acc += sf[p][kk]*sw[c*41+kk];
    out[(p0+p)*64 + c] = acc;
  }
}

// ---------------- instance norm (NHWC): partial sums + atomics ----------------
__global__ __launch_bounds__(256) void stats_kernel(
    const float* __restrict__ x, float* __restrict__ stats){
  int t = threadIdx.x;
  int c = t&63, pg = t>>6;
  size_t base = (size_t)blockIdx.x*256;
  float s=0.f, sq=0.f;
  for (int g2=0; g2<64; g2++){
    float v = x[(base + g2*4 + pg)*64 + c];
    s += v; sq += v*v;
  }
  __shared__ float rs[256], rq[256];
  rs[t]=s; rq[t]=sq;
  __syncthreads();
  if (t<128){ rs[t]+=rs[t+128]; rq[t]+=rq[t+128]; }
  __syncthreads();
  if (t<64){
    atomicAdd(&stats[t],    rs[t]+rs[t+64]);
    atomicAdd(&stats[64+t], rq[t]+rq[t+64]);
  }
}

__global__ __launch_bounds__(256) void norm_elu_kernel(
    float* __restrict__ x, const float* __restrict__ stats){
  size_t i4 = ((size_t)blockIdx.x*256 + threadIdx.x)*4;
  int c0 = (int)(i4 & 63);
  floatx4 v = *(const floatx4*)(x + i4);
  #pragma unroll
  for (int k=0;k<4;k++){
    int c = c0+k;
    float mu = stats[c]*(1.f/NPIX);
    float var = stats[64+c]*(1.f/NPIX) - mu*mu;
    float rsg = rsqrtf(var + 1e-5f);
    float vv = (v[k]-mu)*rsg;
    v[k] = vv>0.f ? vv : expm1f(vv);
  }
  *(floatx4*)(x+i4) = v;
}

__global__ __launch_bounds__(256) void norm_res_elu_kernel(
    const float* __restrict__ tin, float* __restrict__ x, const float* __restrict__ stats){
  size_t i4 = ((size_t)blockIdx.x*256 + threadIdx.x)*4;
  int c0 = (int)(i4 & 63);
  floatx4 tv = *(const floatx4*)(tin + i4);
  floatx4 xv = *(const floatx4*)(x + i4);
  #pragma unroll
  for (int k=0;k<4;k++){
    int c = c0+k;
    float mu = stats[c]*(1.f/NPIX);
    float var = stats[64+c]*(1.f/NPIX) - mu*mu;
    float rsg = rsqrtf(var + 1e-5f);
    float vv = (tv[k]-mu)*rsg + xv[k];
    xv[k] = vv>0.f ? vv : expm1f(vv);
  }
  *(floatx4*)(x+i4) = xv;
}

// ---------------- attention ----------------
__global__ __launch_bounds__(256) void g_partial_kernel(
    const float* __restrict__ td, float* __restrict__ GC){
  size_t base = (size_t)blockIdx.x*256;
  float cnt = (td[base + threadIdx.x] > 0.f) ? 1.f : 0.f;
  __shared__ float red[256];
  red[threadIdx.x]=cnt; __syncthreads();
  for (int st=128; st; st>>=1){
    if (threadIdx.x<st) red[threadIdx.x]+=red[threadIdx.x+st];
    __syncthreads();
  }
  if (threadIdx.x==0) atomicAdd(GC, red[0]);
}

__global__ void g_final_kernel(
    const float* __restrict__ GC, const float* __restrict__ tq,
    const float* __restrict__ w1, const float* __restrict__ b1,
    const float* __restrict__ w2, const float* __restrict__ b2,
    float* __restrict__ G){
  if (threadIdx.x==0){
    float f0 = GC[0]*(1.f/NPIX), f1 = tq[0], f2 = (float)LDIM/512.f;
    float z = b2[0];
    for (int j=0;j<16;j++){
      float h = f0*w1[j] + f1*w1[16+j] + f2*w1[32+j] + b1[j];
      z += (h>0.f?h:0.f)*w2[j];
    }
    G[0] = sigf(z);
  }
}

__global__ __launch_bounds__(256) void q_proj_kernel(
    const float* __restrict__ x, const float* __restrict__ wq, float* __restrict__ q){
  __shared__ float xs[64][65];
  __shared__ float wsh[2048];
  size_t pb = (size_t)blockIdx.x*64;
  int c = threadIdx.x & 63;
  for (int p = threadIdx.x>>6; p<64; p+=4) xs[p][c] = x[(pb+p)*64 + c];
  for (int idx=threadIdx.x; idx<2048; idx+=256) wsh[idx]=wq[idx];
  __syncthreads();
  #pragma unroll
  for (int k=0;k<8;k++){
    int idx = threadIdx.x + k*256;
    int p = idx>>5, n = idx&31;
    float acc=0.f;
    #pragma unroll
    for (int cc=0;cc<64;cc++) acc += xs[p][cc]*wsh[cc*32+n];
    q[(pb+p)*32 + n] = acc;
  }
}

__global__ __launch_bounds__(256) void proj_left_kernel(
    const float* __restrict__ x, const float* __restrict__ wl, const float* __restrict__ wvl,
    float* __restrict__ left, float* __restrict__ vleft){
  int i = blockIdx.x;
  __shared__ float xa[32][65];
  __shared__ float w1s[2048], w2s[2048];
  int c = threadIdx.x & 63;
  for (int a = threadIdx.x>>6; a<32; a+=4)
    xa[a][c] = x[((size_t)i*LDIM + 12*a)*64 + c];
  for (int idx=threadIdx.x; idx<2048; idx+=256){ w1s[idx]=wl[idx]; w2s[idx]=wvl[idx]; }
  __syncthreads();
  #pragma unroll
  for (int k=0;k<4;k++){
    int idx = threadIdx.x + k*256;
    int a = idx>>5, n = idx&31;
    float a1=0.f, a2=0.f;
    #pragma unroll
    for (int cc=0;cc<64;cc++){ float v=xa[a][cc]; a1+=v*w1s[cc*32+n]; a2+=v*w2s[cc*32+n]; }
    left [((size_t)i*32+a)*32+n]=a1;
    vleft[((size_t)i*32+a)*32+n]=a2;
  }
}

__global__ __launch_bounds__(256) void proj_right_kernel(
    const float* __restrict__ x, const float* __restrict__ wr, const float* __restrict__ wvr,
    float* __restrict__ right, float* __restrict__ vright){
  int a = blockIdx.x; int row = 12*a;
  __shared__ float xr[32][65];
  __shared__ float w1s[2048], w2s[2048];
  for (int idx=threadIdx.x; idx<2048; idx+=256){ w1s[idx]=wr[idx]; w2s[idx]=wvr[idx]; }
  int c = threadIdx.x & 63;
  for (int j0=0;j0<LDIM;j0+=32){
    __syncthreads();
    for (int jl = threadIdx.x>>6; jl<32; jl+=4)
      xr[jl][c] = x[((size_t)row*LDIM + j0 + jl)*64 + c];
    __syncthreads();
    #pragma unroll
    for (int k=0;k<4;k++){
      int idx=threadIdx.x+k*256; int jl=idx>>5, n=idx&31;
      float a1=0.f, a2=0.f;
      #pragma unroll
      for (int cc=0;cc<64;cc++){ float v=xr[jl][cc]; a1+=v*w1s[cc*32+n]; a2+=v*w2s[cc*32+n]; }
      right [((size_t)(j0+jl)*32 + a)*32 + n]=a1;
      vright[((size_t)(j0+jl)*32 + a)*32 + n]=a2;
    }
  }
}

__global__ __launch_bounds__(128) void scores_kernel(
    const float* __restrict__ q, const float* __restrict__ left,
    const float* __restrict__ right, const float* __restrict__ td,
    const float* __restrict__ gp, float* __restrict__ attn){
  int i = blockIdx.y;
  int j = blockIdx.x*128 + threadIdx.x;
  __shared__ float lf[1024];
  __shared__ float tl[32];
  for (int idx=threadIdx.x; idx<1024; idx+=128) lf[idx] = left[(size_t)i*1024 + idx];
  if (threadIdx.x<32) tl[threadIdx.x] = td[i*LDIM + 12*threadIdx.x];
  __syncthreads();
  float g = gp[0];
  float qv[32];
  const float* qp = q + ((size_t)i*LDIM+j)*32;
  #pragma unroll
  for (int n=0;n<32;n++) qv[n]=qp[n];
  float tdij = td[i*LDIM+j];
  float s[32];
  const float* rp = right + (size_t)j*1024;
  float m = -1e30f;
  #pragma unroll
  for (int a=0;a<32;a++){
    float acc=0.f;
    #pragma unroll
    for (int n=0;n<32;n++) acc += qv[n]*lf[a*32+n];
    #pragma unroll
    for (int n=0;n<32;n++) acc += qv[n]*rp[a*32+n];
    acc *= 0.17677669529663687f;
    float tr = td[(12*a)*LDIM + j];
    float bias = -fabsf(tl[a] + tr - tdij) * (1.0f/12.0f);
    acc += g*bias;
    s[a]=acc;
    m = fmaxf(m, acc);
  }
  float sum=0.f;
  #pragma unroll
  for (int a=0;a<32;a++){ s[a]=expf(s[a]-m); sum+=s[a]; }
  float inv = 1.f/sum;
  float* op = attn + ((size_t)i*LDIM+j)*32;
  #pragma unroll
  for (int a=0;a<32;a++) op[a] = s[a]*inv;
}

__global__ __launch_bounds__(256) void update_kernel(
    const float* __restrict__ attn, const float* __restrict__ vleft,
    const float* __restrict__ vright, float* __restrict__ upd){
  int i = blockIdx.y;
  int j0 = blockIdx.x*8;
  int p = threadIdx.x>>5, n = threadIdx.x&31;
  __shared__ float at[8][33];
  __shared__ float vl[1024];
  at[p][n] = attn[((size_t)i*LDIM + j0+p)*32 + n];
  for (int idx=threadIdx.x; idx<1024; idx+=256) vl[idx]=vleft[(size_t)i*1024+idx];
  __syncthreads();
  const float* vr = vright + (size_t)(j0+p)*1024;
  float acc=0.f;
  #pragma unroll
  for (int a=0;a<32;a++){
    float w = at[p][a];
    acc += w*vl[a*32+n];
    acc += w*vr[a*32+n];
  }
  upd[((size_t)i*LDIM + j0+p)*32 + n] = acc;
}

__global__ __launch_bounds__(256) void gate_out_kernel(
    float* __restrict__ x, const float* __restrict__ upd,
    const float* __restrict__ wg, const float* __restrict__ bg,
    const float* __restrict__ wo){
  __shared__ float wgs[4096];
  __shared__ float wos[2048];
  __shared__ float xs[16][65];
  __shared__ float us[16][33];
  size_t pb = (size_t)blockIdx.x*16;
  int t = threadIdx.x;
  for (int idx=t; idx<4096; idx+=256) wgs[idx]=wg[idx];
  for (int idx=t; idx<2048; idx+=256) wos[idx]=wo[idx];
  {
    int c = t&63;
    for (int p=t>>6; p<16; p+=4) xs[p][c] = x[(pb+p)*64+c];
  }
  for (int idx=t; idx<512; idx+=256){
    int p = idx>>5, n = idx&31;
    us[p][n] = upd[(pb+p)*32+n];
  }
  __syncthreads();
  #pragma unroll
  for (int k=0;k<4;k++){
    int item = t + k*256;
    int c = item&63, p = item>>6;
    float gacc = bg[c];
    #pragma unroll
    for (int cc=0;cc<64;cc++) gacc += xs[p][cc]*wgs[cc*64+c];
    float uacc=0.f;
    #pragma unroll
    for (int n=0;n<32;n++) uacc += us[p][n]*wos[n*64+c];
    x[(pb+p)*64+c] = xs[p][c] + sigf(gacc)*uacc;
  }
}

// ---------------- heads ----------------
__global__ __launch_bounds__(256) void sym_kernel(
    const float* __restrict__ lg, float* __restrict__ symb, float* __restrict__ dout){
  int i = blockIdx.y;
  int j = blockIdx.x*4 + (threadIdx.x>>6);
  int o = threadIdx.x & 63;
  float v = 0.5f*(lg[((size_t)i*LDIM+j)*64+o] + lg[((size_t)j*LDIM+i)*64+o]);
  size_t pix = (size_t)i*LDIM+j;
  symb[pix*64+o] = (o<63)? v : 0.f;
  if (o<63) dout[pix*63+o] = v;
}

__global__ __launch_bounds__(256) void conf_kernel(
    const float* __restrict__ c2, const float* __restrict__ w,
    const float* __restrict__ b, float* __restrict__ out){
  int t = threadIdx.x;
  size_t pix = (size_t)blockIdx.x*8 + (t>>5);
  int c = t&31;
  float v = c2[pix*32 + c]*w[c];
  #pragma unroll
  for (int off=16; off; off>>=1) v += __shfl_xor(v, off);
  if (c==0) out[pix] = sigf(v + b[0]);
}

extern "C" void kernel_launch(void* const* d_in, const int* in_sizes, int n_in,
                              void* d_out, int out_size, void* d_ws, size_t ws_size,
                              hipStream_t stream){
  const float* feat = (const float*)d_in[0];
  const float* td   = (const float*)d_in[1];
  const float* tq   = (const float*)d_in[2];
  const float* in_w = (const float*)d_in[3];
  const float* in_b = (const float*)d_in[4];
  const float* c1w  = (const float*)d_in[5];
  const float* c1b  = (const float*)d_in[6];
  const float* c2w  = (const float*)d_in[7];
  const float* c2b  = (const float*)d_in[8];
  const float* wq   = (const float*)d_in[9];
  const float* wl   = (const float*)d_in[10];
  const float* wr   = (const float*)d_in[11];
  const float* wvl  = (const float*)d_in[12];
  const float* wvr  = (const float*)d_in[13];
  const float* wo   = (const float*)d_in[14];
  const float* wg   = (const float*)d_in[15];
  const float* bg   = (const float*)d_in[16];
  const float* tgw1 = (const float*)d_in[17];
  const float* tgb1 = (const float*)d_in[18];
  const float* tgw2 = (const float*)d_in[19];
  const float* tgb2 = (const float*)d_in[20];
  const float* dw   = (const float*)d_in[21];
  const float* db   = (const float*)d_in[22];
  const float* cf1w = (const float*)d_in[23];
  const float* cf1b = (const float*)d_in[24];
  const float* cf2w = (const float*)d_in[25];
  const float* cf2b = (const float*)d_in[26];
  const float* cf3w = (const float*)d_in[27];
  const float* cf3b = (const float*)d_in[28];

  float* ws = (float*)d_ws;
  const size_t BUF = (size_t)64*NPIX;
  float* X   = ws;
  float* T1  = ws + BUF;
  float* T2  = ws + 2*BUF;
  float* STATS = ws + 3*BUF;            // 12 slots x 128 floats
  float* G     = STATS + 1536;          // g value
  float* GC    = G + 1;                 // coverage count accumulator
  __bf16* WF   = (__bf16*)(G + 16);     // prepped weights, 506880 bf16

  // attention temporaries (T1/T2 free during attention)
  float* Q      = T1;                    // 32*NPIX
  float* LEFTB  = T1 + (size_t)32*NPIX;  // 384*32*32
  float* RIGHTB = LEFTB + 393216;
  float* VLEFT  = RIGHTB + 393216;
  float* VRIGHT = VLEFT + 393216;
  float* ATTN   = T2;
  float* UPD    = T1;                    // reuse Q region after scores

  hipMemsetAsync(STATS, 0, (1536 + 16)*sizeof(float), stream);
  prep_kernel<<<1980, 256, 0, stream>>>(c1w, c2w, dw, cf1w, cf2w, WF);
  g_partial_kernel<<<576, 256, 0, stream>>>(td, GC);
  g_final_kernel<<<1, 64, 0, stream>>>(GC, tq, tgw1, tgb1, tgw2, tgb2, G);

  in_proj_kernel<<<9216, 256, 0, stream>>>(feat, in_w, in_b, X);

  const int dils[6] = {1,2,4,8,16,1};
  for (int i=0;i<6;i++){
    int d = dils[i];
    size_t lds1 = (size_t)(128+2*d)*72*2*2;
    size_t lds2 = (size_t)(128+2*1)*72*2*2;
    mfma_conv<64,4><<<dim3(3,LDIM), 256, lds1, stream>>>(
        X, WF + (size_t)(2*i)*36864, c1b + i*64, 64, T1, d, 0);
    stats_kernel<<<576, 256, 0, stream>>>(T1, STATS + (2*i)*128);
    norm_elu_kernel<<<9216, 256, 0, stream>>>(T1, STATS + (2*i)*128);
    mfma_conv<64,4><<<dim3(3,LDIM), 256, lds2, stream>>>(
        T1, WF + (size_t)(2*i+1)*36864, c2b + i*64, 64, T2, 1, 0);
    stats_kernel<<<576, 256, 0, stream>>>(T2, STATS + (2*i+1)*128);
    norm_res_elu_kernel<<<9216, 256, 0, stream>>>(T2, X, STATS + (2*i+1)*128);
    if (i%2==1){
      q_proj_kernel<<<2304, 256, 0, stream>>>(X, wq, Q);
      proj_left_kernel<<<384, 256, 0, stream>>>(X, wl, wvl, LEFTB, VLEFT);
      proj_right_kernel<<<32, 256, 0, stream>>>(X, wr, wvr, RIGHTB, VRIGHT);
      scores_kernel<<<dim3(3,LDIM), 128, 0, stream>>>(Q, LEFTB, RIGHTB, td, G, ATTN);
      update_kernel<<<dim3(48,LDIM), 256, 0, stream>>>(ATTN, VLEFT, VRIGHT, UPD);
      gate_out_kernel<<<9216, 256, 0, stream>>>(X, UPD, wg, bg, wo);
    }
  }

  size_t lds_d1_64 = (size_t)130*72*2*2;
  size_t lds_d1_32 = (size_t)130*40*2*2;
  // distance head (OC 63 padded to 64; pad channel = 0)
  mfma_conv<64,4><<<dim3(3,LDIM), 256, lds_d1_64, stream>>>(
      X, WF + 442368, db, 63, T1, 1, 0);
  sym_kernel<<<dim3(96,LDIM), 256, 0, stream>>>(T1, T2, (float*)d_out);
  // confidence head
  mfma_conv<64,2><<<dim3(3,LDIM), 256, lds_d1_64, stream>>>(
      T2, WF + 479232, cf1b, 32, X, 1, 1);
  mfma_conv<32,2><<<dim3(3,LDIM), 256, lds_d1_32, stream>>>(
      X, WF + 497664, cf2b, 32, T1, 1, 1);
  conf_kernel<<<18432, 256, 0, stream>>>(T1, cf3w, cf3b, (float*)d_out + (size_t)NPIX*NBINS);
}